// Round 1
// baseline (8001.311 us; speedup 1.0000x reference)
//
#include <hip/hip_runtime.h>
#include <hip/hip_bf16.h>
#include <math.h>

// Problem constants
#define BB 4
#define TT 1536
#define CC 1536
#define HH 8
#define KK 64
#define VV 192
#define FF 192
#define EE 1536   // H*V
#define HK 512    // H*K
#define P2 3071   // 2T-1

// ---------------------------------------------------------------------------
// Positional features, pass 1: raw values per position m (one thread per m).
// Layout pe_half[m][0:32]=exp, [32:64]=central mask, [64:96]=gamma prob (raw).
// Also atomicMax of gamma prob into gmax (positive floats -> uint compare ok).
// ---------------------------------------------------------------------------
__global__ void pos_raw_kernel(float* __restrict__ pe_half, unsigned int* __restrict__ gmax) {
  int m = blockIdx.x * blockDim.x + threadIdx.x;
  if (m >= P2) return;
  float p = (float)(m - (TT - 1));
  float ap = fabsf(p);
  const int fs = FF / 6;  // 32
  float* row = pe_half + (size_t)m * (FF / 2);

  // exponential: exp(-ln2/half_life * ap) = 2^(-ap/half_life)
  const double lo = 3.0, hi = log2((double)TT);
  for (int i = 0; i < fs; ++i) {
    double hl = exp2(lo + (hi - lo) * (double)i / (double)(fs - 1));
    row[i] = exp2f((float)(-(double)ap / hl));
  }
  // central mask: widths = 2^(i+1) - 1
  for (int i = 0; i < fs; ++i) {
    float w = exp2f((float)(i + 1)) - 1.0f;
    row[fs + i] = (w > ap) ? 1.0f : 0.0f;
  }
  // gamma pdf
  float lmax = 0.0f;
  const float stddev = (float)TT / (2.0f * (float)fs);  // 24
  for (int i = 0; i < fs; ++i) {
    float mean = (float)((double)TT / fs + ((double)TT - (double)TT / fs) * (double)i / (double)(fs - 1));
    float conc = (mean / stddev) * (mean / stddev);
    float rate = mean / (stddev * stddev);
    float logp;
    if (ap > 0.0f)
      logp = (conc - 1.0f) * logf(ap) - rate * ap - (lgammaf(conc) - conc * logf(rate));
    else
      logp = -INFINITY;  // xlogy with conc-1>0, ap=0
    float prob = expf(logp) + 1e-8f;
    row[2 * fs + i] = prob;
    lmax = fmaxf(lmax, prob);
  }
  atomicMax(gmax, __float_as_uint(lmax));
}

// ---------------------------------------------------------------------------
// Positional features, pass 2: normalize gamma, assemble full pe with sign copy
// pe[m][f] for f<96 = emb; pe[m][96+f] = sign(p)*emb
// ---------------------------------------------------------------------------
__global__ void pos_assemble_kernel(const float* __restrict__ pe_half,
                                    const unsigned int* __restrict__ gmax,
                                    float* __restrict__ pe) {
  int idx = blockIdx.x * blockDim.x + threadIdx.x;
  if (idx >= P2 * (FF / 2)) return;
  int m = idx / (FF / 2);
  int f = idx % (FF / 2);
  float val = pe_half[idx];
  if (f >= 2 * (FF / 6)) val = val / __uint_as_float(*gmax);
  float p = (float)(m - (TT - 1));
  float sign = (p > 0.0f) ? 1.0f : ((p < 0.0f) ? -1.0f : 0.0f);
  pe[(size_t)m * FF + f] = val;
  pe[(size_t)m * FF + (FF / 2) + f] = sign * val;
}

// ---------------------------------------------------------------------------
// SGEMM: C[M,N] = A[M,Kd] @ B[N,Kd]^T (+ bias[N]). 64x64 tile, 4x4/thread.
// Kd must be a multiple of 16 (true here: 1536, 192).
// ---------------------------------------------------------------------------
template <bool HAS_BIAS>
__global__ __launch_bounds__(256) void sgemm_nt(const float* __restrict__ A,
                                                const float* __restrict__ Bw,
                                                const float* __restrict__ bias,
                                                float* __restrict__ Cc,
                                                int M, int N, int Kd) {
  __shared__ float As[16][64];
  __shared__ float Bs[16][64];
  int tid = threadIdx.x;
  int tx = tid & 15, ty = tid >> 4;
  int row0 = blockIdx.y * 64, col0 = blockIdx.x * 64;
  int lr = tid >> 2;          // 0..63
  int lk = (tid & 3) << 2;    // 0,4,8,12
  float acc[4][4] = {};
  for (int kt = 0; kt < Kd; kt += 16) {
    int ar = row0 + lr;
    float4 av = make_float4(0.f, 0.f, 0.f, 0.f);
    if (ar < M) av = *(const float4*)(A + (size_t)ar * Kd + kt + lk);
    As[lk + 0][lr] = av.x; As[lk + 1][lr] = av.y; As[lk + 2][lr] = av.z; As[lk + 3][lr] = av.w;
    int br = col0 + lr;
    float4 bv = make_float4(0.f, 0.f, 0.f, 0.f);
    if (br < N) bv = *(const float4*)(Bw + (size_t)br * Kd + kt + lk);
    Bs[lk + 0][lr] = bv.x; Bs[lk + 1][lr] = bv.y; Bs[lk + 2][lr] = bv.z; Bs[lk + 3][lr] = bv.w;
    __syncthreads();
#pragma unroll
    for (int kk = 0; kk < 16; ++kk) {
      float a[4], b[4];
#pragma unroll
      for (int i = 0; i < 4; ++i) a[i] = As[kk][ty * 4 + i];
#pragma unroll
      for (int j = 0; j < 4; ++j) b[j] = Bs[kk][tx * 4 + j];
#pragma unroll
      for (int i = 0; i < 4; ++i)
#pragma unroll
        for (int j = 0; j < 4; ++j) acc[i][j] += a[i] * b[j];
    }
    __syncthreads();
  }
#pragma unroll
  for (int i = 0; i < 4; ++i) {
    int r = row0 + ty * 4 + i;
    if (r >= M) continue;
#pragma unroll
    for (int j = 0; j < 4; ++j) {
      int c = col0 + tx * 4 + j;
      if (c < N) {
        float v = acc[i][j];
        if (HAS_BIAS) v += bias[c];
        Cc[(size_t)r * N + c] = v;
      }
    }
  }
}

// ---------------------------------------------------------------------------
// Fused attention: one block per (q-row, head, batch).
// logit[j] = (q*s + rwb) . k[j]  +  (q*s + rrb) . r_k[T-1+j-q]   (rel shift)
// then softmax over j, then out[v] = sum_j w[j] * V[j,v].
// ---------------------------------------------------------------------------
__global__ __launch_bounds__(256) void attn_kernel(const float* __restrict__ q,
                                                   const float* __restrict__ k,
                                                   const float* __restrict__ v,
                                                   const float* __restrict__ rk,
                                                   const float* __restrict__ rwb,
                                                   const float* __restrict__ rrb,
                                                   float* __restrict__ aout) {
  int t0 = blockIdx.x, h = blockIdx.y, b = blockIdx.z;
  int tid = threadIdx.x;
  __shared__ float qw[KK], qr[KK];
  __shared__ float logit[TT];
  __shared__ float red[256];

  if (tid < KK) {
    float qv = q[((size_t)(b * TT + t0)) * HK + h * KK + tid] * 0.125f;  // K^-0.5
    qw[tid] = qv + rwb[h * KK + tid];
    qr[tid] = qv + rrb[h * KK + tid];
  }
  __syncthreads();

  // logits
  for (int j = tid; j < TT; j += 256) {
    const float4* krow = (const float4*)(k + ((size_t)(b * TT + j)) * HK + h * KK);
    const float4* rrow = (const float4*)(rk + ((size_t)(TT - 1 + j - t0)) * HK + h * KK);
    float c = 0.f, r = 0.f;
#pragma unroll
    for (int g = 0; g < KK / 4; ++g) {
      float4 kv = krow[g];
      float4 rv = rrow[g];
      c += qw[g * 4 + 0] * kv.x + qw[g * 4 + 1] * kv.y + qw[g * 4 + 2] * kv.z + qw[g * 4 + 3] * kv.w;
      r += qr[g * 4 + 0] * rv.x + qr[g * 4 + 1] * rv.y + qr[g * 4 + 2] * rv.z + qr[g * 4 + 3] * rv.w;
    }
    logit[j] = c + r;
  }
  __syncthreads();

  // softmax: max
  float lm = -1e30f;
  for (int j = tid; j < TT; j += 256) lm = fmaxf(lm, logit[j]);
  red[tid] = lm;
  __syncthreads();
  for (int s = 128; s > 0; s >>= 1) {
    if (tid < s) red[tid] = fmaxf(red[tid], red[tid + s]);
    __syncthreads();
  }
  float mx = red[0];
  __syncthreads();
  // exp + sum
  float ls = 0.f;
  for (int j = tid; j < TT; j += 256) {
    float e = expf(logit[j] - mx);
    logit[j] = e;
    ls += e;
  }
  red[tid] = ls;
  __syncthreads();
  for (int s = 128; s > 0; s >>= 1) {
    if (tid < s) red[tid] += red[tid + s];
    __syncthreads();
  }
  float inv = 1.0f / red[0];
  __syncthreads();

  // PV: 192 threads own one v-column each
  if (tid < VV) {
    const float* vbase = v + (size_t)(b * TT) * EE + h * VV + tid;
    float a0 = 0.f, a1 = 0.f, a2 = 0.f, a3 = 0.f;
    for (int j = 0; j < TT; j += 4) {
      a0 += logit[j + 0] * vbase[(size_t)(j + 0) * EE];
      a1 += logit[j + 1] * vbase[(size_t)(j + 1) * EE];
      a2 += logit[j + 2] * vbase[(size_t)(j + 2) * EE];
      a3 += logit[j + 3] * vbase[(size_t)(j + 3) * EE];
    }
    aout[((size_t)(b * TT + t0)) * EE + h * VV + tid] = ((a0 + a1) + (a2 + a3)) * inv;
  }
}

// ---------------------------------------------------------------------------
extern "C" void kernel_launch(void* const* d_in, const int* in_sizes, int n_in,
                              void* d_out, int out_size, void* d_ws, size_t ws_size,
                              hipStream_t stream) {
  const float* x   = (const float*)d_in[0];
  const float* Wq  = (const float*)d_in[1];
  const float* Wk  = (const float*)d_in[2];
  const float* Wv  = (const float*)d_in[3];
  const float* Wrk = (const float*)d_in[4];
  const float* rwb = (const float*)d_in[5];
  const float* rrb = (const float*)d_in[6];
  const float* We  = (const float*)d_in[7];
  const float* be  = (const float*)d_in[8];
  float* out = (float*)d_out;

  float* wsf = (float*)d_ws;
  unsigned int* gmax = (unsigned int*)wsf;                 // 1 cell (+pad)
  float* pe_half = wsf + 64;                               // 3071*96
  float* pe      = pe_half + (size_t)P2 * (FF / 2);        // 3071*192
  float* rk      = pe + (size_t)P2 * FF;                   // 3071*512
  float* qb      = rk + (size_t)P2 * HK;                   // 6144*512
  float* kb      = qb + (size_t)BB * TT * HK;              // 6144*512
  float* vb      = kb + (size_t)BB * TT * HK;              // 6144*1536
  float* ab      = vb + (size_t)BB * TT * EE;              // 6144*1536

  hipMemsetAsync(gmax, 0, sizeof(unsigned int), stream);

  pos_raw_kernel<<<(P2 + 255) / 256, 256, 0, stream>>>(pe_half, gmax);
  pos_assemble_kernel<<<(P2 * (FF / 2) + 255) / 256, 256, 0, stream>>>(pe_half, gmax, pe);

  const int M = BB * TT;  // 6144
  // r_k = pe @ Wrk^T  : [3071, 512]
  sgemm_nt<false><<<dim3(HK / 64, (P2 + 63) / 64), 256, 0, stream>>>(pe, Wrk, nullptr, rk, P2, HK, FF);
  // q = x @ Wq^T, k = x @ Wk^T : [6144, 512]
  sgemm_nt<false><<<dim3(HK / 64, M / 64), 256, 0, stream>>>(x, Wq, nullptr, qb, M, HK, CC);
  sgemm_nt<false><<<dim3(HK / 64, M / 64), 256, 0, stream>>>(x, Wk, nullptr, kb, M, HK, CC);
  // v = x @ Wv^T : [6144, 1536]
  sgemm_nt<false><<<dim3(EE / 64, M / 64), 256, 0, stream>>>(x, Wv, nullptr, vb, M, EE, CC);

  // fused attention
  attn_kernel<<<dim3(TT, HH, BB), 256, 0, stream>>>(qb, kb, vb, rk, rwb, rrb, ab);

  // final projection with bias
  sgemm_nt<true><<<dim3(EE / 64, M / 64), 256, 0, stream>>>(ab, We, be, out, M, EE, EE);
}

// Round 3
// 1651.180 us; speedup vs baseline: 4.8458x; 4.8458x over previous
//
#include <hip/hip_runtime.h>
#include <hip/hip_bf16.h>
#include <math.h>

// Problem constants
#define BB 4
#define TT 1536
#define CC 1536
#define HH 8
#define KK 64
#define VV 192
#define FF 192
#define EE 1536   // H*V
#define HK 512    // H*K
#define P2 3071   // 2T-1
#define RKROWS 3072  // P2 + 1 pad row (band edge, value never used)

typedef __attribute__((ext_vector_type(8))) __bf16 bf16x8;
typedef __attribute__((ext_vector_type(4))) float f32x4;
typedef __attribute__((ext_vector_type(4))) unsigned short us4;
typedef __attribute__((ext_vector_type(8))) unsigned short us8;

__device__ __forceinline__ unsigned short f2bf(float f) {
  union { float f; unsigned int u; } x; x.f = f;
  unsigned int r = x.u + 0x7fffu + ((x.u >> 16) & 1u);
  return (unsigned short)(r >> 16);
}

// ---------------------------------------------------------------------------
// Positional features, pass 1 (unchanged from r1, validated)
// ---------------------------------------------------------------------------
__global__ void pos_raw_kernel(float* __restrict__ pe_half, unsigned int* __restrict__ gmax) {
  int m = blockIdx.x * blockDim.x + threadIdx.x;
  if (m >= P2) return;
  float p = (float)(m - (TT - 1));
  float ap = fabsf(p);
  const int fs = FF / 6;  // 32
  float* row = pe_half + (size_t)m * (FF / 2);

  const double lo = 3.0, hi = log2((double)TT);
  for (int i = 0; i < fs; ++i) {
    double hl = exp2(lo + (hi - lo) * (double)i / (double)(fs - 1));
    row[i] = exp2f((float)(-(double)ap / hl));
  }
  for (int i = 0; i < fs; ++i) {
    float w = exp2f((float)(i + 1)) - 1.0f;
    row[fs + i] = (w > ap) ? 1.0f : 0.0f;
  }
  float lmax = 0.0f;
  const float stddev = (float)TT / (2.0f * (float)fs);
  for (int i = 0; i < fs; ++i) {
    float mean = (float)((double)TT / fs + ((double)TT - (double)TT / fs) * (double)i / (double)(fs - 1));
    float conc = (mean / stddev) * (mean / stddev);
    float rate = mean / (stddev * stddev);
    float logp;
    if (ap > 0.0f)
      logp = (conc - 1.0f) * logf(ap) - rate * ap - (lgammaf(conc) - conc * logf(rate));
    else
      logp = -INFINITY;
    float prob = expf(logp) + 1e-8f;
    row[2 * fs + i] = prob;
    lmax = fmaxf(lmax, prob);
  }
  atomicMax(gmax, __float_as_uint(lmax));
}

__global__ void pos_assemble_kernel(const float* __restrict__ pe_half,
                                    const unsigned int* __restrict__ gmax,
                                    float* __restrict__ pe) {
  int idx = blockIdx.x * blockDim.x + threadIdx.x;
  if (idx >= P2 * (FF / 2)) return;
  int m = idx / (FF / 2);
  int f = idx % (FF / 2);
  float val = pe_half[idx];
  if (f >= 2 * (FF / 6)) val = val / __uint_as_float(*gmax);
  float p = (float)(m - (TT - 1));
  float sign = (p > 0.0f) ? 1.0f : ((p < 0.0f) ? -1.0f : 0.0f);
  pe[(size_t)m * FF + f] = val;
  pe[(size_t)m * FF + (FF / 2) + f] = sign * val;
}

// ---------------------------------------------------------------------------
// SGEMM: C[M,N] = A[M,Kd] @ B[N,Kd]^T with mode-specific epilogues.
// MODE 1: f32 out + bias.
// MODE 2: qprep  -> Qwh/Qrh bf16 [b][h][t][64]  (val*0.125 + rwb / + rrb)
// MODE 3: kprep  -> Kh bf16 [b][h][t][64]
// MODE 4: rkprep -> Rkh bf16 [h][3072][64] (rows 0..3070 written)
// MODE 5: vprep  -> Vt bf16 [b][h][v][t] (transposed)
// ---------------------------------------------------------------------------
template <int MODE>
__global__ __launch_bounds__(256) void sgemm_nt(const float* __restrict__ A,
                                                const float* __restrict__ Bw,
                                                const float* __restrict__ bias,
                                                const float* __restrict__ bias2,
                                                float* __restrict__ Cc,
                                                unsigned short* __restrict__ O1,
                                                unsigned short* __restrict__ O2,
                                                int M, int N, int Kd) {
  __shared__ float As[16][64];
  __shared__ float Bs[16][64];
  int tid = threadIdx.x;
  int tx = tid & 15, ty = tid >> 4;
  int row0 = blockIdx.y * 64, col0 = blockIdx.x * 64;
  int lr = tid >> 2;
  int lk = (tid & 3) << 2;
  float acc[4][4] = {};
  for (int kt = 0; kt < Kd; kt += 16) {
    int ar = row0 + lr;
    float4 av = make_float4(0.f, 0.f, 0.f, 0.f);
    if (ar < M) av = *(const float4*)(A + (size_t)ar * Kd + kt + lk);
    As[lk + 0][lr] = av.x; As[lk + 1][lr] = av.y; As[lk + 2][lr] = av.z; As[lk + 3][lr] = av.w;
    int br = col0 + lr;
    float4 bv = make_float4(0.f, 0.f, 0.f, 0.f);
    if (br < N) bv = *(const float4*)(Bw + (size_t)br * Kd + kt + lk);
    Bs[lk + 0][lr] = bv.x; Bs[lk + 1][lr] = bv.y; Bs[lk + 2][lr] = bv.z; Bs[lk + 3][lr] = bv.w;
    __syncthreads();
#pragma unroll
    for (int kk = 0; kk < 16; ++kk) {
      float a[4], b[4];
#pragma unroll
      for (int i = 0; i < 4; ++i) a[i] = As[kk][ty * 4 + i];
#pragma unroll
      for (int j = 0; j < 4; ++j) b[j] = Bs[kk][tx * 4 + j];
#pragma unroll
      for (int i = 0; i < 4; ++i)
#pragma unroll
        for (int j = 0; j < 4; ++j) acc[i][j] += a[i] * b[j];
    }
    __syncthreads();
  }

  int r0e = row0 + ty * 4;
  int c0e = col0 + tx * 4;

  if (MODE == 1) {
#pragma unroll
    for (int i = 0; i < 4; ++i) {
      int r = r0e + i;
      if (r >= M) continue;
#pragma unroll
      for (int j = 0; j < 4; ++j) {
        int c = c0e + j;
        if (c < N) Cc[(size_t)r * N + c] = acc[i][j] + bias[c];
      }
    }
  } else if (MODE == 2) {
    // q: two bf16 outputs with biases; M=B*T, N=512
    int b = r0e / TT;
    int h = c0e / KK, k0 = c0e % KK;
#pragma unroll
    for (int i = 0; i < 4; ++i) {
      int t = (r0e + i) % TT;
      size_t di = ((((size_t)b * HH + h) * TT + t) * KK + k0);
      us4 w1, w2;
#pragma unroll
      for (int j = 0; j < 4; ++j) {
        float qv = acc[i][j] * 0.125f;
        w1[j] = f2bf(qv + bias[c0e + j]);
        w2[j] = f2bf(qv + bias2[c0e + j]);
      }
      *(us4*)(O1 + di) = w1;
      *(us4*)(O2 + di) = w2;
    }
  } else if (MODE == 3) {
    int b = r0e / TT;
    int h = c0e / KK, k0 = c0e % KK;
#pragma unroll
    for (int i = 0; i < 4; ++i) {
      int t = (r0e + i) % TT;
      size_t di = ((((size_t)b * HH + h) * TT + t) * KK + k0);
      us4 w1;
#pragma unroll
      for (int j = 0; j < 4; ++j) w1[j] = f2bf(acc[i][j]);
      *(us4*)(O1 + di) = w1;
    }
  } else if (MODE == 4) {
    int h = c0e / KK, k0 = c0e % KK;
#pragma unroll
    for (int i = 0; i < 4; ++i) {
      int r = r0e + i;
      if (r >= M) continue;
      size_t di = (((size_t)h * RKROWS + r) * KK + k0);
      us4 w1;
#pragma unroll
      for (int j = 0; j < 4; ++j) w1[j] = f2bf(acc[i][j]);
      *(us4*)(O1 + di) = w1;
    }
  } else if (MODE == 5) {
    // Vt[b][h][v][t]; pack along i (t consecutive)
    int b = r0e / TT;
    int t0 = r0e % TT;
    int h = c0e / VV, v0 = c0e % VV;
#pragma unroll
    for (int j = 0; j < 4; ++j) {
      size_t di = ((((size_t)b * HH + h) * VV + (v0 + j)) * TT + t0);
      us4 w1;
#pragma unroll
      for (int i = 0; i < 4; ++i) w1[i] = f2bf(acc[i][j]);
      *(us4*)(O1 + di) = w1;
    }
  }
}

// ---------------------------------------------------------------------------
// MFMA flash attention with fused relative shift.
// Grid: (T/64, H, B); 256 threads = 4 waves; wave w owns q-strip rows w*16..+16.
// Per kv tile (64 keys):
//   C = Qw(64xK) @ K_tile^T           -> C_lds[64][64]
//   G = Qr(64xK) @ Rk[band 128]^T     -> G_lds[64][128]; rel[qq][jj]=G[qq][jj-qq+63]
//   online softmax (4 thr/row) -> P bf16 in P_lds; O frags rescaled, PV via MFMA.
// ---------------------------------------------------------------------------
__global__ __launch_bounds__(256) void attn_mfma(const unsigned short* __restrict__ Qwh,
                                                 const unsigned short* __restrict__ Qrh,
                                                 const unsigned short* __restrict__ Kh,
                                                 const unsigned short* __restrict__ Rkh,
                                                 const unsigned short* __restrict__ Vt,
                                                 float* __restrict__ ab) {
  const int q0 = blockIdx.x * 64;
  const int h = blockIdx.y, b = blockIdx.z;
  const int tid = threadIdx.x;
  const int wave = tid >> 6, lane = tid & 63;
  const int fr = lane & 15, fq = lane >> 4;
  const int kof = fq * 8;

  __shared__ float C_lds[64][65];
  __shared__ float G_lds[64][132];
  __shared__ unsigned short P_lds[64][72];
  __shared__ float scl[64];
  __shared__ float sfin[64];

  const unsigned short* Qwp = Qwh + (((size_t)b * HH + h) * TT) * KK;
  const unsigned short* Qrp = Qrh + (((size_t)b * HH + h) * TT) * KK;
  const unsigned short* Kp  = Kh  + (((size_t)b * HH + h) * TT) * KK;
  const unsigned short* Rp  = Rkh + (size_t)h * RKROWS * KK;
  const unsigned short* Vp  = Vt  + (((size_t)b * HH + h) * VV) * TT;

  // A-operand fragments (held for whole block)
  bf16x8 aw[2], arr[2];
  {
    int qrow = q0 + wave * 16 + fr;
    const unsigned short* qw = Qwp + (size_t)qrow * KK;
    const unsigned short* qr = Qrp + (size_t)qrow * KK;
    aw[0]  = *(const bf16x8*)(qw + kof);
    aw[1]  = *(const bf16x8*)(qw + 32 + kof);
    arr[0] = *(const bf16x8*)(qr + kof);
    arr[1] = *(const bf16x8*)(qr + 32 + kof);
  }

  f32x4 oacc[12];
#pragma unroll
  for (int i = 0; i < 12; ++i) oacc[i] = (f32x4){0.f, 0.f, 0.f, 0.f};

  const int srow = tid >> 2;          // softmax row 0..63
  const int scg = (tid & 3) * 16;     // softmax col group
  float m_run = -INFINITY, s_run = 0.0f;

  for (int j0 = 0; j0 < TT; j0 += 64) {
    // ---- content logits ----
    f32x4 cfr[4];
#pragma unroll
    for (int tj = 0; tj < 4; ++tj) {
      f32x4 acc = (f32x4){0.f, 0.f, 0.f, 0.f};
#pragma unroll
      for (int ks = 0; ks < 2; ++ks) {
        bf16x8 bv = *(const bf16x8*)(Kp + (size_t)(j0 + tj * 16 + fr) * KK + ks * 32 + kof);
        acc = __builtin_amdgcn_mfma_f32_16x16x32_bf16(aw[ks], bv, acc, 0, 0, 0);
      }
      cfr[tj] = acc;
    }
    // ---- rel band logits ----
    int r0 = (TT - 1) + j0 - q0 - 63;  // always in [0, 2T-128]
    f32x4 gfr[8];
#pragma unroll
    for (int tj = 0; tj < 8; ++tj) {
      f32x4 acc = (f32x4){0.f, 0.f, 0.f, 0.f};
#pragma unroll
      for (int ks = 0; ks < 2; ++ks) {
        bf16x8 bv = *(const bf16x8*)(Rp + (size_t)(r0 + tj * 16 + fr) * KK + ks * 32 + kof);
        acc = __builtin_amdgcn_mfma_f32_16x16x32_bf16(arr[ks], bv, acc, 0, 0, 0);
      }
      gfr[tj] = acc;
    }
    // ---- store logit tiles to LDS ----
#pragma unroll
    for (int tj = 0; tj < 4; ++tj)
#pragma unroll
      for (int rr = 0; rr < 4; ++rr)
        C_lds[wave * 16 + fq * 4 + rr][tj * 16 + fr] = cfr[tj][rr];
#pragma unroll
    for (int tj = 0; tj < 8; ++tj)
#pragma unroll
      for (int rr = 0; rr < 4; ++rr)
        G_lds[wave * 16 + fq * 4 + rr][tj * 16 + fr] = gfr[tj][rr];
    __syncthreads();  // (b) C,G visible; prev-iter PV reads of P done

    // ---- online softmax partial (4 threads per row) ----
    float lv[16];
    float pm = -3.0e38f;
#pragma unroll
    for (int t = 0; t < 16; ++t) {
      int jj = scg + t;
      float val = C_lds[srow][jj] + G_lds[srow][jj - srow + 63];
      lv[t] = val;
      pm = fmaxf(pm, val);
    }
    pm = fmaxf(pm, __shfl_xor(pm, 1));
    pm = fmaxf(pm, __shfl_xor(pm, 2));
    float mnew = fmaxf(m_run, pm);
    float sc = expf(m_run - mnew);
    float ps = 0.0f;
    unsigned short pb[16];
#pragma unroll
    for (int t = 0; t < 16; ++t) {
      float e = expf(lv[t] - mnew);
      ps += e;
      pb[t] = f2bf(e);
    }
    ps += __shfl_xor(ps, 1);
    ps += __shfl_xor(ps, 2);
    s_run = s_run * sc + ps;
    m_run = mnew;
    if ((tid & 3) == 0) scl[srow] = sc;
    us8 w0, w1;
#pragma unroll
    for (int t = 0; t < 8; ++t) { w0[t] = pb[t]; w1[t] = pb[8 + t]; }
    *(us8*)&P_lds[srow][scg] = w0;
    *(us8*)&P_lds[srow][scg + 8] = w1;
    __syncthreads();  // (c) P, scl visible

    // ---- rescale O, then PV ----
    float scr[4];
#pragma unroll
    for (int rr = 0; rr < 4; ++rr) scr[rr] = scl[wave * 16 + fq * 4 + rr];
#pragma unroll
    for (int tv = 0; tv < 12; ++tv)
#pragma unroll
      for (int rr = 0; rr < 4; ++rr) oacc[tv][rr] *= scr[rr];

    bf16x8 pa[2];
#pragma unroll
    for (int ks = 0; ks < 2; ++ks)
      pa[ks] = *(const bf16x8*)&P_lds[wave * 16 + fr][ks * 32 + kof];
#pragma unroll
    for (int tv = 0; tv < 12; ++tv) {
      f32x4 acc = oacc[tv];
#pragma unroll
      for (int ks = 0; ks < 2; ++ks) {
        bf16x8 bv = *(const bf16x8*)(Vp + (size_t)(tv * 16 + fr) * TT + j0 + ks * 32 + kof);
        acc = __builtin_amdgcn_mfma_f32_16x16x32_bf16(pa[ks], bv, acc, 0, 0, 0);
      }
      oacc[tv] = acc;
    }
    // no barrier needed here: next-iter C/G stores don't alias P/scl reads,
    // and next-iter P/scl writes are after barrier (b).
  }

  if ((tid & 3) == 0) sfin[srow] = s_run;
  __syncthreads();
  float inv[4];
#pragma unroll
  for (int rr = 0; rr < 4; ++rr) inv[rr] = 1.0f / sfin[wave * 16 + fq * 4 + rr];
#pragma unroll
  for (int tv = 0; tv < 12; ++tv)
#pragma unroll
    for (int rr = 0; rr < 4; ++rr)
      ab[((size_t)(b * TT + q0 + wave * 16 + fq * 4 + rr)) * EE + h * VV + tv * 16 + fr] =
          oacc[tv][rr] * inv[rr];
}

// ---------------------------------------------------------------------------
extern "C" void kernel_launch(void* const* d_in, const int* in_sizes, int n_in,
                              void* d_out, int out_size, void* d_ws, size_t ws_size,
                              hipStream_t stream) {
  const float* x   = (const float*)d_in[0];
  const float* Wq  = (const float*)d_in[1];
  const float* Wk  = (const float*)d_in[2];
  const float* Wv  = (const float*)d_in[3];
  const float* Wrk = (const float*)d_in[4];
  const float* rwb = (const float*)d_in[5];
  const float* rrb = (const float*)d_in[6];
  const float* We  = (const float*)d_in[7];
  const float* be  = (const float*)d_in[8];
  float* out = (float*)d_out;

  size_t off = 0;
  auto alloc = [&](size_t bytes) -> void* {
    void* p = (char*)d_ws + off;
    off += (bytes + 255) & ~(size_t)255;
    return p;
  };
  unsigned int* gmax = (unsigned int*)alloc(sizeof(unsigned int));
  float* pe_half = (float*)alloc((size_t)P2 * (FF / 2) * 4);
  float* pe      = (float*)alloc((size_t)P2 * FF * 4);
  unsigned short* Qwh = (unsigned short*)alloc((size_t)BB * HH * TT * KK * 2);
  unsigned short* Qrh = (unsigned short*)alloc((size_t)BB * HH * TT * KK * 2);
  unsigned short* Kh  = (unsigned short*)alloc((size_t)BB * HH * TT * KK * 2);
  unsigned short* Rkh = (unsigned short*)alloc((size_t)HH * RKROWS * KK * 2);
  unsigned short* Vt  = (unsigned short*)alloc((size_t)BB * HH * VV * TT * 2);
  float* ab = (float*)alloc((size_t)BB * TT * EE * 4);

  hipMemsetAsync(gmax, 0, sizeof(unsigned int), stream);

  pos_raw_kernel<<<(P2 + 255) / 256, 256, 0, stream>>>(pe_half, gmax);
  pos_assemble_kernel<<<(P2 * (FF / 2) + 255) / 256, 256, 0, stream>>>(pe_half, gmax, pe);

  const int M = BB * TT;  // 6144
  // r_k = pe @ Wrk^T -> Rkh bf16 [h][3072][64]
  sgemm_nt<4><<<dim3(HK / 64, (P2 + 63) / 64), 256, 0, stream>>>(
      pe, Wrk, nullptr, nullptr, nullptr, Rkh, nullptr, P2, HK, FF);
  // q -> Qwh/Qrh bf16
  sgemm_nt<2><<<dim3(HK / 64, M / 64), 256, 0, stream>>>(
      x, Wq, rwb, rrb, nullptr, Qwh, Qrh, M, HK, CC);
  // k -> Kh bf16
  sgemm_nt<3><<<dim3(HK / 64, M / 64), 256, 0, stream>>>(
      x, Wk, nullptr, nullptr, nullptr, Kh, nullptr, M, HK, CC);
  // v -> Vt bf16 (transposed)
  sgemm_nt<5><<<dim3(EE / 64, M / 64), 256, 0, stream>>>(
      x, Wv, nullptr, nullptr, nullptr, Vt, nullptr, M, EE, CC);

  // fused MFMA attention
  attn_mfma<<<dim3(TT / 64, HH, BB), 256, 0, stream>>>(Qwh, Qrh, Kh, Rkh, Vt, ab);

  // final projection with bias (f32)
  sgemm_nt<1><<<dim3(EE / 64, M / 64), 256, 0, stream>>>(
      ab, We, be, nullptr, out, nullptr, nullptr, M, EE, EE);
}

// Round 4
// 701.448 us; speedup vs baseline: 11.4068x; 2.3540x over previous
//
#include <hip/hip_runtime.h>
#include <hip/hip_bf16.h>
#include <math.h>

// Problem constants
#define BB 4
#define TT 1536
#define CC 1536
#define HH 8
#define KK 64
#define VV 192
#define FF 192
#define EE 1536   // H*V
#define HK 512    // H*K
#define P2 3071   // 2T-1
#define RKROWS 3072  // P2 + 1 pad row (read by MFMA band, never used in softmax)

typedef __attribute__((ext_vector_type(8))) __bf16 bf16x8;
typedef __attribute__((ext_vector_type(4))) float f32x4;
typedef __attribute__((ext_vector_type(4))) unsigned short us4;
typedef __attribute__((ext_vector_type(8))) unsigned short us8;

__device__ __forceinline__ unsigned short f2bf(float f) {
  union { float f; unsigned int u; } x; x.f = f;
  unsigned int r = x.u + 0x7fffu + ((x.u >> 16) & 1u);
  return (unsigned short)(r >> 16);
}

__device__ __forceinline__ void gload_lds16(const unsigned short* g, unsigned short* l) {
  __builtin_amdgcn_global_load_lds((const __attribute__((address_space(1))) unsigned int*)g,
                                   (__attribute__((address_space(3))) unsigned int*)l, 16, 0, 0);
}

// ---------------------------------------------------------------------------
// f32 -> bf16 conversion (vectorized), n % 4 == 0
// ---------------------------------------------------------------------------
__global__ void cvt_bf16(const float* __restrict__ in, unsigned short* __restrict__ out, int n4) {
  int i = blockIdx.x * blockDim.x + threadIdx.x;
  if (i >= n4) return;
  float4 v = *(const float4*)(in + (size_t)i * 4);
  us4 w;
  w[0] = f2bf(v.x); w[1] = f2bf(v.y); w[2] = f2bf(v.z); w[3] = f2bf(v.w);
  *(us4*)(out + (size_t)i * 4) = w;
}

// ---------------------------------------------------------------------------
// Positional features, pass 1 (unchanged, validated)
// ---------------------------------------------------------------------------
__global__ void pos_raw_kernel(float* __restrict__ pe_half, unsigned int* __restrict__ gmax) {
  int m = blockIdx.x * blockDim.x + threadIdx.x;
  if (m >= P2) return;
  float p = (float)(m - (TT - 1));
  float ap = fabsf(p);
  const int fs = FF / 6;  // 32
  float* row = pe_half + (size_t)m * (FF / 2);

  const double lo = 3.0, hi = log2((double)TT);
  for (int i = 0; i < fs; ++i) {
    double hl = exp2(lo + (hi - lo) * (double)i / (double)(fs - 1));
    row[i] = exp2f((float)(-(double)ap / hl));
  }
  for (int i = 0; i < fs; ++i) {
    float w = exp2f((float)(i + 1)) - 1.0f;
    row[fs + i] = (w > ap) ? 1.0f : 0.0f;
  }
  float lmax = 0.0f;
  const float stddev = (float)TT / (2.0f * (float)fs);
  for (int i = 0; i < fs; ++i) {
    float mean = (float)((double)TT / fs + ((double)TT - (double)TT / fs) * (double)i / (double)(fs - 1));
    float conc = (mean / stddev) * (mean / stddev);
    float rate = mean / (stddev * stddev);
    float logp;
    if (ap > 0.0f)
      logp = (conc - 1.0f) * logf(ap) - rate * ap - (lgammaf(conc) - conc * logf(rate));
    else
      logp = -INFINITY;
    float prob = expf(logp) + 1e-8f;
    row[2 * fs + i] = prob;
    lmax = fmaxf(lmax, prob);
  }
  atomicMax(gmax, __float_as_uint(lmax));
}

// pass 2: normalize gamma, assemble full pe (bf16) with sign copy
__global__ void pos_assemble_kernel(const float* __restrict__ pe_half,
                                    const unsigned int* __restrict__ gmax,
                                    unsigned short* __restrict__ pe_b) {
  int idx = blockIdx.x * blockDim.x + threadIdx.x;
  if (idx >= P2 * (FF / 2)) return;
  int m = idx / (FF / 2);
  int f = idx % (FF / 2);
  float val = pe_half[idx];
  if (f >= 2 * (FF / 6)) val = val / __uint_as_float(*gmax);
  float p = (float)(m - (TT - 1));
  float sign = (p > 0.0f) ? 1.0f : ((p < 0.0f) ? -1.0f : 0.0f);
  pe_b[(size_t)m * FF + f] = f2bf(val);
  pe_b[(size_t)m * FF + (FF / 2) + f] = f2bf(sign * val);
}

// ---------------------------------------------------------------------------
// bf16 MFMA GEMM: C[M,N] = A[M,Kd] @ B[N,Kd]^T, mode-specific epilogues.
// 128x128 tile, BK=32, 4 waves (2x2 of 64x64), 16x16x32 MFMA.
// Staging via global_load_lds width-16, linear LDS dest; bank swizzle by
// pre-swizzling the global source chunk (slot ^= (row>>1)&3) and applying the
// same XOR on ds_read (both-sides rule).
// MODE 1: f32 out + bias[col].
// MODE 2: Qwh/Qrh bf16 [b][h][t][64]  (acc*0.125 + rwb / + rrb)
// MODE 3: Kh bf16 [b][h][t][64]
// MODE 4: Rkh bf16 [h][3072][64]
// MODE 5: Vt bf16 [b][h][v][t]
// Requires: M%128==0, N%128==0, Kd%32==0 (true for all uses).
// ---------------------------------------------------------------------------
template <int MODE>
__global__ __launch_bounds__(256) void bgemm(const unsigned short* __restrict__ A,
                                             const unsigned short* __restrict__ Bw,
                                             const float* __restrict__ bias,
                                             const float* __restrict__ bias2,
                                             float* __restrict__ Cc,
                                             unsigned short* __restrict__ O1,
                                             unsigned short* __restrict__ O2,
                                             int M, int N, int Kd) {
  __shared__ __align__(16) unsigned short As[128 * 32];
  __shared__ __align__(16) unsigned short Bs[128 * 32];
  const int tid = threadIdx.x;
  const int lane = tid & 63;
  const int wave = tid >> 6;
  const int fr = lane & 15, fq = lane >> 4;
  const int wrow = (wave >> 1) * 64, wcol = (wave & 1) * 64;
  const int row0 = blockIdx.y * 128, col0 = blockIdx.x * 128;

  // staging chunk ids: cid = tid + 256*c, row = cid>>2, slot = cid&3
  const int r_c0 = tid >> 2, s_c0 = tid & 3;
  const int r_c1 = (tid + 256) >> 2, s_c1 = tid & 3;  // (tid+256)&3 == tid&3
  const int sw_c0 = s_c0 ^ ((r_c0 >> 1) & 3);
  const int sw_c1 = s_c1 ^ ((r_c1 >> 1) & 3);
  const unsigned short* Asrc0 = A + (size_t)(row0 + r_c0) * Kd + sw_c0 * 8;
  const unsigned short* Asrc1 = A + (size_t)(row0 + r_c1) * Kd + sw_c1 * 8;
  const unsigned short* Bsrc0 = Bw + (size_t)(col0 + r_c0) * Kd + sw_c0 * 8;
  const unsigned short* Bsrc1 = Bw + (size_t)(col0 + r_c1) * Kd + sw_c1 * 8;
  unsigned short* Adst0 = As + (size_t)tid * 8;
  unsigned short* Adst1 = As + (size_t)(tid + 256) * 8;
  unsigned short* Bdst0 = Bs + (size_t)tid * 8;
  unsigned short* Bdst1 = Bs + (size_t)(tid + 256) * 8;

  // frag LDS offsets (shorts)
  int aoff[4], boff[4];
#pragma unroll
  for (int m = 0; m < 4; ++m) {
    int rl = wrow + m * 16 + fr;
    aoff[m] = rl * 32 + (fq ^ ((rl >> 1) & 3)) * 8;
    int cl = wcol + m * 16 + fr;
    boff[m] = cl * 32 + (fq ^ ((cl >> 1) & 3)) * 8;
  }

  f32x4 acc[4][4];
#pragma unroll
  for (int m = 0; m < 4; ++m)
#pragma unroll
    for (int n = 0; n < 4; ++n) acc[m][n] = (f32x4){0.f, 0.f, 0.f, 0.f};

  for (int kt = 0; kt < Kd; kt += 32) {
    gload_lds16(Asrc0 + kt, Adst0);
    gload_lds16(Asrc1 + kt, Adst1);
    gload_lds16(Bsrc0 + kt, Bdst0);
    gload_lds16(Bsrc1 + kt, Bdst1);
    __syncthreads();  // drains vmcnt before any wave reads LDS

    bf16x8 af[4], bfr[4];
#pragma unroll
    for (int m = 0; m < 4; ++m) af[m] = *(const bf16x8*)(As + aoff[m]);
#pragma unroll
    for (int n = 0; n < 4; ++n) bfr[n] = *(const bf16x8*)(Bs + boff[n]);
#pragma unroll
    for (int m = 0; m < 4; ++m)
#pragma unroll
      for (int n = 0; n < 4; ++n)
        acc[m][n] = __builtin_amdgcn_mfma_f32_16x16x32_bf16(af[m], bfr[n], acc[m][n], 0, 0, 0);
    __syncthreads();  // all ds_reads done before next stage overwrites
  }

  // Epilogue. D[row = fq*4+reg (A-rows), col = fr (B-rows)]
#pragma unroll
  for (int m = 0; m < 4; ++m) {
    int Rbase = row0 + wrow + m * 16 + fq * 4;
#pragma unroll
    for (int n = 0; n < 4; ++n) {
      int Cg = col0 + wcol + n * 16 + fr;
      if (MODE == 1) {
        float bv = bias[Cg];
#pragma unroll
        for (int r = 0; r < 4; ++r)
          Cc[(size_t)(Rbase + r) * N + Cg] = acc[m][n][r] + bv;
      } else if (MODE == 2) {
        int h = Cg >> 6, k0 = Cg & 63;
        float bw = bias[Cg], br = bias2[Cg];
#pragma unroll
        for (int r = 0; r < 4; ++r) {
          int R = Rbase + r;
          int b = R / TT, t = R - b * TT;
          size_t di = ((((size_t)b * HH + h) * TT + t) * KK + k0);
          float qv = acc[m][n][r] * 0.125f;
          O1[di] = f2bf(qv + bw);
          O2[di] = f2bf(qv + br);
        }
      } else if (MODE == 3) {
        int h = Cg >> 6, k0 = Cg & 63;
#pragma unroll
        for (int r = 0; r < 4; ++r) {
          int R = Rbase + r;
          int b = R / TT, t = R - b * TT;
          O1[((((size_t)b * HH + h) * TT + t) * KK + k0)] = f2bf(acc[m][n][r]);
        }
      } else if (MODE == 4) {
        int h = Cg >> 6, k0 = Cg & 63;
#pragma unroll
        for (int r = 0; r < 4; ++r)
          O1[(((size_t)h * RKROWS + (Rbase + r)) * KK + k0)] = f2bf(acc[m][n][r]);
      } else if (MODE == 5) {
        int h = Cg / VV, v0 = Cg - h * VV;
#pragma unroll
        for (int r = 0; r < 4; ++r) {
          int R = Rbase + r;
          int b = R / TT, t = R - b * TT;
          O1[((((size_t)b * HH + h) * VV + v0) * TT + t)] = f2bf(acc[m][n][r]);
        }
      }
    }
  }
}

// ---------------------------------------------------------------------------
// MFMA flash attention with fused relative shift (validated r3).
// Output now bf16 into ab_b [B*T][E].
// ---------------------------------------------------------------------------
__global__ __launch_bounds__(256) void attn_mfma(const unsigned short* __restrict__ Qwh,
                                                 const unsigned short* __restrict__ Qrh,
                                                 const unsigned short* __restrict__ Kh,
                                                 const unsigned short* __restrict__ Rkh,
                                                 const unsigned short* __restrict__ Vt,
                                                 unsigned short* __restrict__ ab) {
  const int q0 = blockIdx.x * 64;
  const int h = blockIdx.y, b = blockIdx.z;
  const int tid = threadIdx.x;
  const int wave = tid >> 6, lane = tid & 63;
  const int fr = lane & 15, fq = lane >> 4;
  const int kof = fq * 8;

  __shared__ float C_lds[64][65];
  __shared__ float G_lds[64][132];
  __shared__ unsigned short P_lds[64][72];
  __shared__ float scl[64];
  __shared__ float sfin[64];

  const unsigned short* Qwp = Qwh + (((size_t)b * HH + h) * TT) * KK;
  const unsigned short* Qrp = Qrh + (((size_t)b * HH + h) * TT) * KK;
  const unsigned short* Kp  = Kh  + (((size_t)b * HH + h) * TT) * KK;
  const unsigned short* Rp  = Rkh + (size_t)h * RKROWS * KK;
  const unsigned short* Vp  = Vt  + (((size_t)b * HH + h) * VV) * TT;

  bf16x8 aw[2], arr[2];
  {
    int qrow = q0 + wave * 16 + fr;
    const unsigned short* qw = Qwp + (size_t)qrow * KK;
    const unsigned short* qr = Qrp + (size_t)qrow * KK;
    aw[0]  = *(const bf16x8*)(qw + kof);
    aw[1]  = *(const bf16x8*)(qw + 32 + kof);
    arr[0] = *(const bf16x8*)(qr + kof);
    arr[1] = *(const bf16x8*)(qr + 32 + kof);
  }

  f32x4 oacc[12];
#pragma unroll
  for (int i = 0; i < 12; ++i) oacc[i] = (f32x4){0.f, 0.f, 0.f, 0.f};

  const int srow = tid >> 2;
  const int scg = (tid & 3) * 16;
  float m_run = -INFINITY, s_run = 0.0f;

  for (int j0 = 0; j0 < TT; j0 += 64) {
    f32x4 cfr[4];
#pragma unroll
    for (int tj = 0; tj < 4; ++tj) {
      f32x4 acc = (f32x4){0.f, 0.f, 0.f, 0.f};
#pragma unroll
      for (int ks = 0; ks < 2; ++ks) {
        bf16x8 bv = *(const bf16x8*)(Kp + (size_t)(j0 + tj * 16 + fr) * KK + ks * 32 + kof);
        acc = __builtin_amdgcn_mfma_f32_16x16x32_bf16(aw[ks], bv, acc, 0, 0, 0);
      }
      cfr[tj] = acc;
    }
    int r0 = (TT - 1) + j0 - q0 - 63;
    f32x4 gfr[8];
#pragma unroll
    for (int tj = 0; tj < 8; ++tj) {
      f32x4 acc = (f32x4){0.f, 0.f, 0.f, 0.f};
#pragma unroll
      for (int ks = 0; ks < 2; ++ks) {
        bf16x8 bv = *(const bf16x8*)(Rp + (size_t)(r0 + tj * 16 + fr) * KK + ks * 32 + kof);
        acc = __builtin_amdgcn_mfma_f32_16x16x32_bf16(arr[ks], bv, acc, 0, 0, 0);
      }
      gfr[tj] = acc;
    }
#pragma unroll
    for (int tj = 0; tj < 4; ++tj)
#pragma unroll
      for (int rr = 0; rr < 4; ++rr)
        C_lds[wave * 16 + fq * 4 + rr][tj * 16 + fr] = cfr[tj][rr];
#pragma unroll
    for (int tj = 0; tj < 8; ++tj)
#pragma unroll
      for (int rr = 0; rr < 4; ++rr)
        G_lds[wave * 16 + fq * 4 + rr][tj * 16 + fr] = gfr[tj][rr];
    __syncthreads();

    float lv[16];
    float pm = -3.0e38f;
#pragma unroll
    for (int t = 0; t < 16; ++t) {
      int jj = scg + t;
      float val = C_lds[srow][jj] + G_lds[srow][jj - srow + 63];
      lv[t] = val;
      pm = fmaxf(pm, val);
    }
    pm = fmaxf(pm, __shfl_xor(pm, 1));
    pm = fmaxf(pm, __shfl_xor(pm, 2));
    float mnew = fmaxf(m_run, pm);
    float sc = expf(m_run - mnew);
    float ps = 0.0f;
    unsigned short pb[16];
#pragma unroll
    for (int t = 0; t < 16; ++t) {
      float e = expf(lv[t] - mnew);
      ps += e;
      pb[t] = f2bf(e);
    }
    ps += __shfl_xor(ps, 1);
    ps += __shfl_xor(ps, 2);
    s_run = s_run * sc + ps;
    m_run = mnew;
    if ((tid & 3) == 0) scl[srow] = sc;
    us8 w0, w1;
#pragma unroll
    for (int t = 0; t < 8; ++t) { w0[t] = pb[t]; w1[t] = pb[8 + t]; }
    *(us8*)&P_lds[srow][scg] = w0;
    *(us8*)&P_lds[srow][scg + 8] = w1;
    __syncthreads();

    float scr[4];
#pragma unroll
    for (int rr = 0; rr < 4; ++rr) scr[rr] = scl[wave * 16 + fq * 4 + rr];
#pragma unroll
    for (int tv = 0; tv < 12; ++tv)
#pragma unroll
      for (int rr = 0; rr < 4; ++rr) oacc[tv][rr] *= scr[rr];

    bf16x8 pa[2];
#pragma unroll
    for (int ks = 0; ks < 2; ++ks)
      pa[ks] = *(const bf16x8*)&P_lds[wave * 16 + fr][ks * 32 + kof];
#pragma unroll
    for (int tv = 0; tv < 12; ++tv) {
      f32x4 acc = oacc[tv];
#pragma unroll
      for (int ks = 0; ks < 2; ++ks) {
        bf16x8 bv = *(const bf16x8*)(Vp + (size_t)(tv * 16 + fr) * TT + j0 + ks * 32 + kof);
        acc = __builtin_amdgcn_mfma_f32_16x16x32_bf16(pa[ks], bv, acc, 0, 0, 0);
      }
      oacc[tv] = acc;
    }
  }

  if ((tid & 3) == 0) sfin[srow] = s_run;
  __syncthreads();
  float inv[4];
#pragma unroll
  for (int rr = 0; rr < 4; ++rr) inv[rr] = 1.0f / sfin[wave * 16 + fq * 4 + rr];
#pragma unroll
  for (int tv = 0; tv < 12; ++tv)
#pragma unroll
    for (int rr = 0; rr < 4; ++rr)
      ab[((size_t)(b * TT + q0 + wave * 16 + fq * 4 + rr)) * EE + h * VV + tv * 16 + fr] =
          f2bf(oacc[tv][rr] * inv[rr]);
}

// ---------------------------------------------------------------------------
extern "C" void kernel_launch(void* const* d_in, const int* in_sizes, int n_in,
                              void* d_out, int out_size, void* d_ws, size_t ws_size,
                              hipStream_t stream) {
  const float* x   = (const float*)d_in[0];
  const float* Wq  = (const float*)d_in[1];
  const float* Wk  = (const float*)d_in[2];
  const float* Wv  = (const float*)d_in[3];
  const float* Wrk = (const float*)d_in[4];
  const float* rwb = (const float*)d_in[5];
  const float* rrb = (const float*)d_in[6];
  const float* We  = (const float*)d_in[7];
  const float* be  = (const float*)d_in[8];
  float* out = (float*)d_out;

  size_t off = 0;
  auto alloc = [&](size_t bytes) -> void* {
    void* p = (char*)d_ws + off;
    off += (bytes + 255) & ~(size_t)255;
    return p;
  };
  unsigned int* gmax = (unsigned int*)alloc(sizeof(unsigned int));
  float* pe_half = (float*)alloc((size_t)P2 * (FF / 2) * 4);
  unsigned short* pe_b = (unsigned short*)alloc((size_t)RKROWS * FF * 2);  // row 3071 = pad
  unsigned short* xb   = (unsigned short*)alloc((size_t)BB * TT * CC * 2);
  unsigned short* Wqb  = (unsigned short*)alloc((size_t)HK * CC * 2);
  unsigned short* Wkb  = (unsigned short*)alloc((size_t)HK * CC * 2);
  unsigned short* Wvb  = (unsigned short*)alloc((size_t)EE * CC * 2);
  unsigned short* Web  = (unsigned short*)alloc((size_t)EE * EE * 2);
  unsigned short* Wrkb = (unsigned short*)alloc((size_t)HK * FF * 2);
  unsigned short* Qwh  = (unsigned short*)alloc((size_t)BB * HH * TT * KK * 2);
  unsigned short* Qrh  = (unsigned short*)alloc((size_t)BB * HH * TT * KK * 2);
  unsigned short* Kh   = (unsigned short*)alloc((size_t)BB * HH * TT * KK * 2);
  unsigned short* Rkh  = (unsigned short*)alloc((size_t)HH * RKROWS * KK * 2);
  unsigned short* Vt   = (unsigned short*)alloc((size_t)BB * HH * VV * TT * 2);
  unsigned short* ab_b = (unsigned short*)alloc((size_t)BB * TT * EE * 2);

  hipMemsetAsync(gmax, 0, sizeof(unsigned int), stream);

  pos_raw_kernel<<<(P2 + 255) / 256, 256, 0, stream>>>(pe_half, gmax);
  pos_assemble_kernel<<<(P2 * (FF / 2) + 255) / 256, 256, 0, stream>>>(pe_half, gmax, pe_b);

  auto cvt = [&](const float* src, unsigned short* dst, size_t n) {
    int n4 = (int)(n / 4);
    cvt_bf16<<<(n4 + 255) / 256, 256, 0, stream>>>(src, dst, n4);
  };
  cvt(x, xb, (size_t)BB * TT * CC);
  cvt(Wq, Wqb, (size_t)HK * CC);
  cvt(Wk, Wkb, (size_t)HK * CC);
  cvt(Wv, Wvb, (size_t)EE * CC);
  cvt(We, Web, (size_t)EE * EE);
  cvt(Wrk, Wrkb, (size_t)HK * FF);

  const int M = BB * TT;  // 6144
  // r_k: [3072, 512] = pe_b @ Wrkb^T -> Rkh [h][3072][64]
  bgemm<4><<<dim3(HK / 128, RKROWS / 128), 256, 0, stream>>>(
      pe_b, Wrkb, nullptr, nullptr, nullptr, Rkh, nullptr, RKROWS, HK, FF);
  // q -> Qwh/Qrh
  bgemm<2><<<dim3(HK / 128, M / 128), 256, 0, stream>>>(
      xb, Wqb, rwb, rrb, nullptr, Qwh, Qrh, M, HK, CC);
  // k -> Kh
  bgemm<3><<<dim3(HK / 128, M / 128), 256, 0, stream>>>(
      xb, Wkb, nullptr, nullptr, nullptr, Kh, nullptr, M, HK, CC);
  // v -> Vt (transposed)
  bgemm<5><<<dim3(EE / 128, M / 128), 256, 0, stream>>>(
      xb, Wvb, nullptr, nullptr, nullptr, Vt, nullptr, M, EE, CC);

  // fused MFMA attention -> bf16 ab
  attn_mfma<<<dim3(TT / 64, HH, BB), 256, 0, stream>>>(Qwh, Qrh, Kh, Rkh, Vt, ab_b);

  // final projection with bias (f32 out)
  bgemm<1><<<dim3(EE / 128, M / 128), 256, 0, stream>>>(
      ab_b, Web, be, nullptr, out, nullptr, nullptr, M, EE, EE);
}

// Round 5
// 586.914 us; speedup vs baseline: 13.6328x; 1.1951x over previous
//
#include <hip/hip_runtime.h>
#include <hip/hip_bf16.h>
#include <math.h>

// Problem constants
#define BB 4
#define TT 1536
#define CC 1536
#define HH 8
#define KK 64
#define VV 192
#define FF 192
#define EE 1536   // H*V
#define HK 512    // H*K
#define P2 3071   // 2T-1
#define RKROWS 3072  // P2 + 1 pad row (read by MFMA band, scatter-masked)

typedef __attribute__((ext_vector_type(8))) __bf16 bf16x8;
typedef __attribute__((ext_vector_type(4))) float f32x4;
typedef __attribute__((ext_vector_type(4))) unsigned short us4;
typedef __attribute__((ext_vector_type(8))) unsigned short us8;

__device__ __forceinline__ unsigned short f2bf(float f) {
  union { float f; unsigned int u; } x; x.f = f;
  unsigned int r = x.u + 0x7fffu + ((x.u >> 16) & 1u);
  return (unsigned short)(r >> 16);
}

__device__ __forceinline__ void gload_lds16(const unsigned short* g, unsigned short* l) {
  __builtin_amdgcn_global_load_lds((const __attribute__((address_space(1))) unsigned int*)g,
                                   (__attribute__((address_space(3))) unsigned int*)l, 16, 0, 0);
}

// ---------------------------------------------------------------------------
// f32 -> bf16 conversion (vectorized), n % 4 == 0
// ---------------------------------------------------------------------------
__global__ void cvt_bf16(const float* __restrict__ in, unsigned short* __restrict__ out, int n4) {
  int i = blockIdx.x * blockDim.x + threadIdx.x;
  if (i >= n4) return;
  float4 v = *(const float4*)(in + (size_t)i * 4);
  us4 w;
  w[0] = f2bf(v.x); w[1] = f2bf(v.y); w[2] = f2bf(v.z); w[3] = f2bf(v.w);
  *(us4*)(out + (size_t)i * 4) = w;
}

// ---------------------------------------------------------------------------
// Positional features, pass 1 (unchanged, validated)
// ---------------------------------------------------------------------------
__global__ void pos_raw_kernel(float* __restrict__ pe_half, unsigned int* __restrict__ gmax) {
  int m = blockIdx.x * blockDim.x + threadIdx.x;
  if (m >= P2) return;
  float p = (float)(m - (TT - 1));
  float ap = fabsf(p);
  const int fs = FF / 6;  // 32
  float* row = pe_half + (size_t)m * (FF / 2);

  const double lo = 3.0, hi = log2((double)TT);
  for (int i = 0; i < fs; ++i) {
    double hl = exp2(lo + (hi - lo) * (double)i / (double)(fs - 1));
    row[i] = exp2f((float)(-(double)ap / hl));
  }
  for (int i = 0; i < fs; ++i) {
    float w = exp2f((float)(i + 1)) - 1.0f;
    row[fs + i] = (w > ap) ? 1.0f : 0.0f;
  }
  float lmax = 0.0f;
  const float stddev = (float)TT / (2.0f * (float)fs);
  for (int i = 0; i < fs; ++i) {
    float mean = (float)((double)TT / fs + ((double)TT - (double)TT / fs) * (double)i / (double)(fs - 1));
    float conc = (mean / stddev) * (mean / stddev);
    float rate = mean / (stddev * stddev);
    float logp;
    if (ap > 0.0f)
      logp = (conc - 1.0f) * logf(ap) - rate * ap - (lgammaf(conc) - conc * logf(rate));
    else
      logp = -INFINITY;
    float prob = expf(logp) + 1e-8f;
    row[2 * fs + i] = prob;
    lmax = fmaxf(lmax, prob);
  }
  atomicMax(gmax, __float_as_uint(lmax));
}

// pass 2: normalize gamma, assemble full pe (bf16) with sign copy
__global__ void pos_assemble_kernel(const float* __restrict__ pe_half,
                                    const unsigned int* __restrict__ gmax,
                                    unsigned short* __restrict__ pe_b) {
  int idx = blockIdx.x * blockDim.x + threadIdx.x;
  if (idx >= P2 * (FF / 2)) return;
  int m = idx / (FF / 2);
  int f = idx % (FF / 2);
  float val = pe_half[idx];
  if (f >= 2 * (FF / 6)) val = val / __uint_as_float(*gmax);
  float p = (float)(m - (TT - 1));
  float sign = (p > 0.0f) ? 1.0f : ((p < 0.0f) ? -1.0f : 0.0f);
  pe_b[(size_t)m * FF + f] = f2bf(val);
  pe_b[(size_t)m * FF + (FF / 2) + f] = f2bf(sign * val);
}

// ---------------------------------------------------------------------------
// bf16 MFMA GEMM (validated r4): 128x128 tile, BK=32, 4 waves, 16x16x32 MFMA.
// ---------------------------------------------------------------------------
template <int MODE>
__global__ __launch_bounds__(256) void bgemm(const unsigned short* __restrict__ A,
                                             const unsigned short* __restrict__ Bw,
                                             const float* __restrict__ bias,
                                             const float* __restrict__ bias2,
                                             float* __restrict__ Cc,
                                             unsigned short* __restrict__ O1,
                                             unsigned short* __restrict__ O2,
                                             int M, int N, int Kd) {
  __shared__ __align__(16) unsigned short As[128 * 32];
  __shared__ __align__(16) unsigned short Bs[128 * 32];
  const int tid = threadIdx.x;
  const int lane = tid & 63;
  const int wave = tid >> 6;
  const int fr = lane & 15, fq = lane >> 4;
  const int wrow = (wave >> 1) * 64, wcol = (wave & 1) * 64;
  const int row0 = blockIdx.y * 128, col0 = blockIdx.x * 128;

  const int r_c0 = tid >> 2, s_c0 = tid & 3;
  const int r_c1 = (tid + 256) >> 2, s_c1 = tid & 3;
  const int sw_c0 = s_c0 ^ ((r_c0 >> 1) & 3);
  const int sw_c1 = s_c1 ^ ((r_c1 >> 1) & 3);
  const unsigned short* Asrc0 = A + (size_t)(row0 + r_c0) * Kd + sw_c0 * 8;
  const unsigned short* Asrc1 = A + (size_t)(row0 + r_c1) * Kd + sw_c1 * 8;
  const unsigned short* Bsrc0 = Bw + (size_t)(col0 + r_c0) * Kd + sw_c0 * 8;
  const unsigned short* Bsrc1 = Bw + (size_t)(col0 + r_c1) * Kd + sw_c1 * 8;
  unsigned short* Adst0 = As + (size_t)tid * 8;
  unsigned short* Adst1 = As + (size_t)(tid + 256) * 8;
  unsigned short* Bdst0 = Bs + (size_t)tid * 8;
  unsigned short* Bdst1 = Bs + (size_t)(tid + 256) * 8;

  int aoff[4], boff[4];
#pragma unroll
  for (int m = 0; m < 4; ++m) {
    int rl = wrow + m * 16 + fr;
    aoff[m] = rl * 32 + (fq ^ ((rl >> 1) & 3)) * 8;
    int cl = wcol + m * 16 + fr;
    boff[m] = cl * 32 + (fq ^ ((cl >> 1) & 3)) * 8;
  }

  f32x4 acc[4][4];
#pragma unroll
  for (int m = 0; m < 4; ++m)
#pragma unroll
    for (int n = 0; n < 4; ++n) acc[m][n] = (f32x4){0.f, 0.f, 0.f, 0.f};

  for (int kt = 0; kt < Kd; kt += 32) {
    gload_lds16(Asrc0 + kt, Adst0);
    gload_lds16(Asrc1 + kt, Adst1);
    gload_lds16(Bsrc0 + kt, Bdst0);
    gload_lds16(Bsrc1 + kt, Bdst1);
    __syncthreads();

    bf16x8 af[4], bfr[4];
#pragma unroll
    for (int m = 0; m < 4; ++m) af[m] = *(const bf16x8*)(As + aoff[m]);
#pragma unroll
    for (int n = 0; n < 4; ++n) bfr[n] = *(const bf16x8*)(Bs + boff[n]);
#pragma unroll
    for (int m = 0; m < 4; ++m)
#pragma unroll
      for (int n = 0; n < 4; ++n)
        acc[m][n] = __builtin_amdgcn_mfma_f32_16x16x32_bf16(af[m], bfr[n], acc[m][n], 0, 0, 0);
    __syncthreads();
  }

#pragma unroll
  for (int m = 0; m < 4; ++m) {
    int Rbase = row0 + wrow + m * 16 + fq * 4;
#pragma unroll
    for (int n = 0; n < 4; ++n) {
      int Cg = col0 + wcol + n * 16 + fr;
      if (MODE == 1) {
        float bv = bias[Cg];
#pragma unroll
        for (int r = 0; r < 4; ++r)
          Cc[(size_t)(Rbase + r) * N + Cg] = acc[m][n][r] + bv;
      } else if (MODE == 2) {
        int h = Cg >> 6, k0 = Cg & 63;
        float bw = bias[Cg], br = bias2[Cg];
#pragma unroll
        for (int r = 0; r < 4; ++r) {
          int R = Rbase + r;
          int b = R / TT, t = R - b * TT;
          size_t di = ((((size_t)b * HH + h) * TT + t) * KK + k0);
          float qv = acc[m][n][r] * 0.125f;
          O1[di] = f2bf(qv + bw);
          O2[di] = f2bf(qv + br);
        }
      } else if (MODE == 3) {
        int h = Cg >> 6, k0 = Cg & 63;
#pragma unroll
        for (int r = 0; r < 4; ++r) {
          int R = Rbase + r;
          int b = R / TT, t = R - b * TT;
          O1[((((size_t)b * HH + h) * TT + t) * KK + k0)] = f2bf(acc[m][n][r]);
        }
      } else if (MODE == 4) {
        int h = Cg >> 6, k0 = Cg & 63;
#pragma unroll
        for (int r = 0; r < 4; ++r)
          O1[(((size_t)h * RKROWS + (Rbase + r)) * KK + k0)] = f2bf(acc[m][n][r]);
      } else if (MODE == 5) {
        int h = Cg / VV, v0 = Cg - h * VV;
#pragma unroll
        for (int r = 0; r < 4; ++r) {
          int R = Rbase + r;
          int b = R / TT, t = R - b * TT;
          O1[((((size_t)b * HH + h) * VV + v0) * TT + t)] = f2bf(acc[m][n][r]);
        }
      }
    }
  }
}

// ---------------------------------------------------------------------------
// Barrier-free wave-local MFMA flash attention with scatter-shift.
// Grid: 768 blocks (XCD-chunk-swizzled), 4 waves; wave owns 16 q-rows.
// Per kv tile (64 keys), per wave:
//   gfr = Qr(16) @ Rk[80-row band]^T  -> scatter L[q][j] at j=band+q-15
//   cfr = Qw(16) @ K_tile^T           -> lv = cfr + L (frag-aligned read)
//   in-register online softmax (4 rows/lane, shfl over fr bits)
//   P = exp written in place into L; PV MFMA reads L rows as A-frags.
// No __syncthreads anywhere: all LDS traffic is wave-local (in-order DS).
// ---------------------------------------------------------------------------
__global__ __launch_bounds__(256, 4) void attn_mfma(const unsigned short* __restrict__ Qwh,
                                                    const unsigned short* __restrict__ Qrh,
                                                    const unsigned short* __restrict__ Kh,
                                                    const unsigned short* __restrict__ Rkh,
                                                    const unsigned short* __restrict__ Vt,
                                                    unsigned short* __restrict__ ab) {
  // XCD-chunk swizzle: 24 consecutive q-blocks (one (h,b) panel) per XCD chunk
  const int bid = blockIdx.x;
  const int Lid = (bid & 7) * 96 + (bid >> 3);
  const int q0 = (Lid % 24) * 64;
  const int yz = Lid / 24;
  const int h = yz & 7, b = yz >> 3;

  const int tid = threadIdx.x;
  const int wave = tid >> 6, lane = tid & 63;
  const int fr = lane & 15, fq = lane >> 4;
  const int kof = fq * 8;
  const int qs = q0 + wave * 16;  // wave's global q-strip start
  const int qlb = fq * 4;         // lane's local q-row base (plus rr)

  __shared__ __align__(16) float Lsm[4][16][68];
  float(*Lw)[68] = Lsm[wave];

  const unsigned short* Qwp = Qwh + (((size_t)b * HH + h) * TT) * KK;
  const unsigned short* Qrp = Qrh + (((size_t)b * HH + h) * TT) * KK;
  const unsigned short* Kp  = Kh  + (((size_t)b * HH + h) * TT) * KK;
  const unsigned short* Rp  = Rkh + (size_t)h * RKROWS * KK;
  const unsigned short* Vp  = Vt  + (((size_t)b * HH + h) * VV) * TT;

  bf16x8 aw[2], arr[2];
  {
    const unsigned short* qw = Qwp + (size_t)(qs + fr) * KK;
    const unsigned short* qr = Qrp + (size_t)(qs + fr) * KK;
    aw[0]  = *(const bf16x8*)(qw + kof);
    aw[1]  = *(const bf16x8*)(qw + 32 + kof);
    arr[0] = *(const bf16x8*)(qr + kof);
    arr[1] = *(const bf16x8*)(qr + 32 + kof);
  }

  f32x4 oacc[12];
#pragma unroll
  for (int i = 0; i < 12; ++i) oacc[i] = (f32x4){0.f, 0.f, 0.f, 0.f};
  float m_run[4] = {-INFINITY, -INFINITY, -INFINITY, -INFINITY};
  float s_run[4] = {0.f, 0.f, 0.f, 0.f};

  for (int j0 = 0; j0 < TT; j0 += 64) {
    // ---- band logits over wave-local 80-row band ----
    const int r0w = (TT - 1) + j0 - qs - 15;
    f32x4 gfr[5];
#pragma unroll
    for (int tjb = 0; tjb < 5; ++tjb) {
      f32x4 acc = (f32x4){0.f, 0.f, 0.f, 0.f};
#pragma unroll
      for (int ks = 0; ks < 2; ++ks) {
        bf16x8 bv = *(const bf16x8*)(Rp + (size_t)(r0w + tjb * 16 + fr) * KK + ks * 32 + kof);
        acc = __builtin_amdgcn_mfma_f32_16x16x32_bf16(arr[ks], bv, acc, 0, 0, 0);
      }
      gfr[tjb] = acc;
    }
    // scatter-shift: L[q][j], j = band + q - 15 (masked to tile)
#pragma unroll
    for (int tjb = 0; tjb < 5; ++tjb)
#pragma unroll
      for (int rr = 0; rr < 4; ++rr) {
        int j = tjb * 16 + fr + qlb + rr - 15;
        if (j >= 0 && j < 64) Lw[qlb + rr][j] = gfr[tjb][rr];
      }

    // ---- content logits ----
    f32x4 cfr[4];
#pragma unroll
    for (int tj = 0; tj < 4; ++tj) {
      f32x4 acc = (f32x4){0.f, 0.f, 0.f, 0.f};
#pragma unroll
      for (int ks = 0; ks < 2; ++ks) {
        bf16x8 bv = *(const bf16x8*)(Kp + (size_t)(j0 + tj * 16 + fr) * KK + ks * 32 + kof);
        acc = __builtin_amdgcn_mfma_f32_16x16x32_bf16(aw[ks], bv, acc, 0, 0, 0);
      }
      cfr[tj] = acc;
    }

    // ---- combine + in-register online softmax (rows q = qlb+rr, cols fr+16tj) ----
    float lvv[4][4];
#pragma unroll
    for (int tj = 0; tj < 4; ++tj)
#pragma unroll
      for (int rr = 0; rr < 4; ++rr)
        lvv[tj][rr] = cfr[tj][rr] + Lw[qlb + rr][tj * 16 + fr];

    float sc[4];
#pragma unroll
    for (int rr = 0; rr < 4; ++rr) {
      float mx = fmaxf(fmaxf(lvv[0][rr], lvv[1][rr]), fmaxf(lvv[2][rr], lvv[3][rr]));
      mx = fmaxf(mx, __shfl_xor(mx, 1));
      mx = fmaxf(mx, __shfl_xor(mx, 2));
      mx = fmaxf(mx, __shfl_xor(mx, 4));
      mx = fmaxf(mx, __shfl_xor(mx, 8));
      float mnew = fmaxf(m_run[rr], mx);
      sc[rr] = __expf(m_run[rr] - mnew);
      m_run[rr] = mnew;
      float p0 = __expf(lvv[0][rr] - mnew);
      float p1 = __expf(lvv[1][rr] - mnew);
      float p2 = __expf(lvv[2][rr] - mnew);
      float p3 = __expf(lvv[3][rr] - mnew);
      Lw[qlb + rr][0 * 16 + fr] = p0;
      Lw[qlb + rr][1 * 16 + fr] = p1;
      Lw[qlb + rr][2 * 16 + fr] = p2;
      Lw[qlb + rr][3 * 16 + fr] = p3;
      float s = (p0 + p1) + (p2 + p3);
      s += __shfl_xor(s, 1);
      s += __shfl_xor(s, 2);
      s += __shfl_xor(s, 4);
      s += __shfl_xor(s, 8);
      s_run[rr] = s_run[rr] * sc[rr] + s;
    }

    // ---- rescale O (PV D-rows share the lane's q mapping) ----
#pragma unroll
    for (int tv = 0; tv < 12; ++tv)
#pragma unroll
      for (int rr = 0; rr < 4; ++rr) oacc[tv][rr] *= sc[rr];

    // ---- PV: A-frag = P rows (lane reads row fr, cols kof.. in-wave) ----
    bf16x8 pa[2];
#pragma unroll
    for (int ks = 0; ks < 2; ++ks) {
      f32x4 plo = *(const f32x4*)&Lw[fr][ks * 32 + kof];
      f32x4 phi = *(const f32x4*)&Lw[fr][ks * 32 + kof + 4];
      union { us8 u; bf16x8 v; } cv;
      cv.u[0] = f2bf(plo[0]); cv.u[1] = f2bf(plo[1]);
      cv.u[2] = f2bf(plo[2]); cv.u[3] = f2bf(plo[3]);
      cv.u[4] = f2bf(phi[0]); cv.u[5] = f2bf(phi[1]);
      cv.u[6] = f2bf(phi[2]); cv.u[7] = f2bf(phi[3]);
      pa[ks] = cv.v;
    }
#pragma unroll
    for (int tv = 0; tv < 12; ++tv) {
      f32x4 acc = oacc[tv];
#pragma unroll
      for (int ks = 0; ks < 2; ++ks) {
        bf16x8 bv = *(const bf16x8*)(Vp + (size_t)(tv * 16 + fr) * TT + j0 + ks * 32 + kof);
        acc = __builtin_amdgcn_mfma_f32_16x16x32_bf16(pa[ks], bv, acc, 0, 0, 0);
      }
      oacc[tv] = acc;
    }
  }

  float inv[4];
#pragma unroll
  for (int rr = 0; rr < 4; ++rr) inv[rr] = 1.0f / s_run[rr];
#pragma unroll
  for (int tv = 0; tv < 12; ++tv)
#pragma unroll
    for (int rr = 0; rr < 4; ++rr)
      ab[((size_t)(b * TT + qs + qlb + rr)) * EE + h * VV + tv * 16 + fr] =
          f2bf(oacc[tv][rr] * inv[rr]);
}

// ---------------------------------------------------------------------------
extern "C" void kernel_launch(void* const* d_in, const int* in_sizes, int n_in,
                              void* d_out, int out_size, void* d_ws, size_t ws_size,
                              hipStream_t stream) {
  const float* x   = (const float*)d_in[0];
  const float* Wq  = (const float*)d_in[1];
  const float* Wk  = (const float*)d_in[2];
  const float* Wv  = (const float*)d_in[3];
  const float* Wrk = (const float*)d_in[4];
  const float* rwb = (const float*)d_in[5];
  const float* rrb = (const float*)d_in[6];
  const float* We  = (const float*)d_in[7];
  const float* be  = (const float*)d_in[8];
  float* out = (float*)d_out;

  size_t off = 0;
  auto alloc = [&](size_t bytes) -> void* {
    void* p = (char*)d_ws + off;
    off += (bytes + 255) & ~(size_t)255;
    return p;
  };
  unsigned int* gmax = (unsigned int*)alloc(sizeof(unsigned int));
  float* pe_half = (float*)alloc((size_t)P2 * (FF / 2) * 4);
  unsigned short* pe_b = (unsigned short*)alloc((size_t)RKROWS * FF * 2);  // row 3071 = pad
  unsigned short* xb   = (unsigned short*)alloc((size_t)BB * TT * CC * 2);
  unsigned short* Wqb  = (unsigned short*)alloc((size_t)HK * CC * 2);
  unsigned short* Wkb  = (unsigned short*)alloc((size_t)HK * CC * 2);
  unsigned short* Wvb  = (unsigned short*)alloc((size_t)EE * CC * 2);
  unsigned short* Web  = (unsigned short*)alloc((size_t)EE * EE * 2);
  unsigned short* Wrkb = (unsigned short*)alloc((size_t)HK * FF * 2);
  unsigned short* Qwh  = (unsigned short*)alloc((size_t)BB * HH * TT * KK * 2);
  unsigned short* Qrh  = (unsigned short*)alloc((size_t)BB * HH * TT * KK * 2);
  unsigned short* Kh   = (unsigned short*)alloc((size_t)BB * HH * TT * KK * 2);
  unsigned short* Rkh  = (unsigned short*)alloc((size_t)HH * RKROWS * KK * 2);
  unsigned short* Vt   = (unsigned short*)alloc((size_t)BB * HH * VV * TT * 2);
  unsigned short* ab_b = (unsigned short*)alloc((size_t)BB * TT * EE * 2);

  hipMemsetAsync(gmax, 0, sizeof(unsigned int), stream);

  pos_raw_kernel<<<(P2 + 255) / 256, 256, 0, stream>>>(pe_half, gmax);
  pos_assemble_kernel<<<(P2 * (FF / 2) + 255) / 256, 256, 0, stream>>>(pe_half, gmax, pe_b);

  auto cvt = [&](const float* src, unsigned short* dst, size_t n) {
    int n4 = (int)(n / 4);
    cvt_bf16<<<(n4 + 255) / 256, 256, 0, stream>>>(src, dst, n4);
  };
  cvt(x, xb, (size_t)BB * TT * CC);
  cvt(Wq, Wqb, (size_t)HK * CC);
  cvt(Wk, Wkb, (size_t)HK * CC);
  cvt(Wv, Wvb, (size_t)EE * CC);
  cvt(We, Web, (size_t)EE * EE);
  cvt(Wrk, Wrkb, (size_t)HK * FF);

  const int M = BB * TT;  // 6144
  bgemm<4><<<dim3(HK / 128, RKROWS / 128), 256, 0, stream>>>(
      pe_b, Wrkb, nullptr, nullptr, nullptr, Rkh, nullptr, RKROWS, HK, FF);
  bgemm<2><<<dim3(HK / 128, M / 128), 256, 0, stream>>>(
      xb, Wqb, rwb, rrb, nullptr, Qwh, Qrh, M, HK, CC);
  bgemm<3><<<dim3(HK / 128, M / 128), 256, 0, stream>>>(
      xb, Wkb, nullptr, nullptr, nullptr, Kh, nullptr, M, HK, CC);
  bgemm<5><<<dim3(EE / 128, M / 128), 256, 0, stream>>>(
      xb, Wvb, nullptr, nullptr, nullptr, Vt, nullptr, M, EE, CC);

  // barrier-free wave-local MFMA attention -> bf16 ab
  attn_mfma<<<dim3(TT / 64 * HH * BB), 256, 0, stream>>>(Qwh, Qrh, Kh, Rkh, Vt, ab_b);

  // final projection with bias (f32 out)
  bgemm<1><<<dim3(EE / 128, M / 128), 256, 0, stream>>>(
      ab_b, Web, be, nullptr, out, nullptr, nullptr, M, EE, EE);
}